// Round 1
// baseline (725.755 us; speedup 1.0000x reference)
//
#include <hip/hip_runtime.h>
#include <hip/hip_bf16.h>

#define CCH 128
#define HHH 128
#define WWW 128
#define HWX 16384           // H*W
#define NHD 4
#define HD  32
#define SCALE 0.17677669529663687f

typedef unsigned int  u32;
typedef unsigned short u16;

__device__ __forceinline__ float bflo(u32 u) { return __uint_as_float(u << 16); }
__device__ __forceinline__ float bfhi(u32 u) { return __uint_as_float(u & 0xffff0000u); }
__device__ __forceinline__ u16 f2bf(float f) {
  u32 u = __float_as_uint(f);
  u += 0x7fffu + ((u >> 16) & 1u);
  return (u16)(u >> 16);
}
__device__ __forceinline__ void st_bf4(u16* p, const float4 a) {
  ushort4 r;
  r.x = f2bf(a.x); r.y = f2bf(a.y); r.z = f2bf(a.z); r.w = f2bf(a.w);
  *(ushort4*)p = r;
}
__device__ __forceinline__ void fma4(float4& a, float s, const float4 w) {
  a.x += s * w.x; a.y += s * w.y; a.z += s * w.z; a.w += s * w.w;
}
__device__ __forceinline__ float dot8(const float* qf, uint4 kk) {
  return qf[0]*bflo(kk.x) + qf[1]*bfhi(kk.x) + qf[2]*bflo(kk.y) + qf[3]*bfhi(kk.y)
       + qf[4]*bflo(kk.z) + qf[5]*bfhi(kk.z) + qf[6]*bflo(kk.w) + qf[7]*bfhi(kk.w);
}
__device__ __forceinline__ void axpy8(float* o, float w, uint4 vv) {
  o[0] += w*bflo(vv.x); o[1] += w*bfhi(vv.x); o[2] += w*bflo(vv.y); o[3] += w*bfhi(vv.y);
  o[4] += w*bflo(vv.z); o[5] += w*bfhi(vv.z); o[6] += w*bflo(vv.w); o[7] += w*bfhi(vv.w);
}

// ---------------- weight transpose: wT[c][384] (q rows pre-scaled), wTp[c][128]
__global__ __launch_bounds__(256) void wtrans_kernel(
    const float* __restrict__ qk_w, const float* __restrict__ v_w,
    const float* __restrict__ proj_w, float* __restrict__ wT, float* __restrict__ wTp) {
  int idx = blockIdx.x * 256 + threadIdx.x;          // 0..65535
  if (idx < 49152) {
    int c = idx / 384, oc = idx % 384;
    float val;
    if (oc < 256) { val = qk_w[oc * 128 + c]; if (oc < 128) val *= SCALE; }
    else          { val = v_w[(oc - 256) * 128 + c]; }
    wT[idx] = val;
  } else {
    int r = idx - 49152;                             // 0..16383
    int c = r >> 7, oc = r & 127;
    wTp[r] = proj_w[oc * 128 + c];
  }
}

// ---------------- argmax over sims[pix][256] -> L[pix], first-index tie-break
__global__ __launch_bounds__(256) void argmax_kernel(
    const float* __restrict__ sims, int* __restrict__ L) {
  const int wave = threadIdx.x >> 6, lane = threadIdx.x & 63;
  const int pix = blockIdx.x * 4 + wave;
  const float4 s4 = *(const float4*)(sims + (size_t)pix * 256 + lane * 4);
  float bv = s4.x; int bi = lane * 4;
  if (s4.y > bv) { bv = s4.y; bi = lane * 4 + 1; }
  if (s4.z > bv) { bv = s4.z; bi = lane * 4 + 2; }
  if (s4.w > bv) { bv = s4.w; bi = lane * 4 + 3; }
  #pragma unroll
  for (int off = 32; off > 0; off >>= 1) {
    float ov = __shfl_down(bv, off);
    int   oi = __shfl_down(bi, off);
    if (ov > bv || (ov == bv && oi < bi)) { bv = ov; bi = oi; }
  }
  if (lane == 0) L[pix] = bi;
}

// ---------------- QKV GEMM: x[b][c][hw] @ wT -> q fp32 [pix][128], k/v bf16 [pix][128]
__global__ __launch_bounds__(256) void qkv_kernel(
    const float* __restrict__ x, const float* __restrict__ wT,
    float* __restrict__ q, u16* __restrict__ kb, u16* __restrict__ vb) {
  __shared__ __align__(16) float xs[128 * 68];
  const int t = threadIdx.x;
  const int pg0 = blockIdx.x * 64;
  const int b = blockIdx.x >> 8;
  const int hw0 = pg0 & (HWX - 1);
  const float* xb = x + (size_t)b * (CCH * HWX) + hw0;
  const int lp = t & 63, lc = t >> 6;
  #pragma unroll
  for (int it = 0; it < 32; ++it) {
    int c = lc + it * 4;
    xs[c * 68 + lp] = xb[(size_t)c * HWX + lp];
  }
  __syncthreads();

  const int ocg = t & 15, pixg = t >> 4;
  const int pixb = pixg * 4;
  float4 acc[4][6];
  #pragma unroll
  for (int p = 0; p < 4; ++p)
    #pragma unroll
    for (int j = 0; j < 6; ++j) acc[p][j] = make_float4(0.f, 0.f, 0.f, 0.f);

  const float* wbase = wT + ocg * 4;
  #pragma unroll 2
  for (int c = 0; c < 128; ++c) {
    const float4 xv = *(const float4*)(xs + c * 68 + pixb);
    const float xa[4] = {xv.x, xv.y, xv.z, xv.w};
    const float* wc = wbase + c * 384;
    float4 w[6];
    #pragma unroll
    for (int j = 0; j < 6; ++j) w[j] = *(const float4*)(wc + 64 * j);
    #pragma unroll
    for (int p = 0; p < 4; ++p)
      #pragma unroll
      for (int j = 0; j < 6; ++j) fma4(acc[p][j], xa[p], w[j]);
  }

  #pragma unroll
  for (int p = 0; p < 4; ++p) {
    const size_t pr = (size_t)(pg0 + pixb + p);
    float* qr = q + (pr << 7) + ocg * 4;
    *(float4*)qr        = acc[p][0];
    *(float4*)(qr + 64) = acc[p][1];
    u16* kr = kb + (pr << 7) + ocg * 4;
    st_bf4(kr,      acc[p][2]);
    st_bf4(kr + 64, acc[p][3]);
    u16* vr = vb + (pr << 7) + ocg * 4;
    st_bf4(vr,      acc[p][4]);
    st_bf4(vr + 64, acc[p][5]);
  }
}

// ---------------- attention: block = 16x16 query tile, 1 head
#define TPAD 40
__global__ __launch_bounds__(256) void attn_kernel(
    const float* __restrict__ q, const u16* __restrict__ kb, const u16* __restrict__ vb,
    const int* __restrict__ L, float* __restrict__ ao) {
  __shared__ __align__(16) u16 kt[484 * TPAD];
  __shared__ __align__(16) u16 vt[484 * TPAD];
  __shared__ int lt[484];
  const int t = threadIdx.x;
  const int bid = blockIdx.x;
  const int h = bid & 3, tj = (bid >> 2) & 7, ti = (bid >> 5) & 7, b = bid >> 8;
  const int i0 = ti * 16, j0 = tj * 16;
  const int r0 = max(0, i0 - 3), r1 = min(HHH - 1, i0 + 18);
  const int c0 = max(0, j0 - 3), c1 = min(WWW - 1, j0 + 18);
  const int nr = r1 - r0 + 1, nc = c1 - c0 + 1;
  const int npix = nr * nc;
  const size_t bbase = (size_t)b * HWX;

  #pragma unroll
  for (int it = 0; it < 8; ++it) {
    int fl = t + it * 256;
    int p = fl >> 2, dq = fl & 3;
    if (p < npix) {
      int rr = p / nc, cc2 = p - rr * nc;
      size_t g = ((bbase + (size_t)(r0 + rr) * WWW + (c0 + cc2)) << 7) + h * HD + dq * 8;
      *(uint4*)(kt + p * TPAD + dq * 8) = *(const uint4*)(kb + g);
      *(uint4*)(vt + p * TPAD + dq * 8) = *(const uint4*)(vb + g);
    }
  }
  for (int it = 0; it < 2; ++it) {
    int p = t + it * 256;
    if (p < npix) {
      int rr = p / nc, cc2 = p - rr * nc;
      lt[p] = L[bbase + (size_t)(r0 + rr) * WWW + (c0 + cc2)];
    }
  }
  __syncthreads();

  const int qi = i0 + (t >> 4), qj = j0 + (t & 15);
  const int slab = ((qi >> 3) << 4) | (qj >> 3);
  const int rs = min(max(qi - 3, 0), HHH - 7) - r0;
  const int cs = min(max(qj - 3, 0), WWW - 7) - c0;

  union { float4 v4[8]; float f[32]; } qu;
  const float* qp = q + ((bbase + (size_t)qi * WWW + qj) << 7) + h * HD;
  #pragma unroll
  for (int u = 0; u < 8; ++u) qu.v4[u] = *(const float4*)(qp + u * 4);

  float lg[49];
  unsigned long long pm = 0ull;
  #pragma unroll
  for (int di = 0; di < 7; ++di) {
    #pragma unroll
    for (int dj = 0; dj < 7; ++dj) {
      const int p = (rs + di) * nc + (cs + dj);
      const u16* kp = kt + p * TPAD;
      float s = 0.f;
      #pragma unroll
      for (int u = 0; u < 4; ++u) {
        uint4 kk = *(const uint4*)(kp + u * 8);
        s += dot8(qu.f + u * 8, kk);
      }
      const int ii = di * 7 + dj;
      lg[ii] = s;
      if (lt[p] == slab) pm |= (1ull << ii);
    }
  }

  float mx = lg[0];
  #pragma unroll
  for (int ii = 1; ii < 49; ++ii) mx = fmaxf(mx, lg[ii]);
  float sa = 0.f, smv = 0.f;
  #pragma unroll
  for (int ii = 0; ii < 49; ++ii) {
    float e = __expf(lg[ii] - mx);
    lg[ii] = e;
    sa += e;
    if ((pm >> ii) & 1ull) smv += e;
  }
  const float inv = 1.f / (smv + 1e-8f * sa);

  float of[32];
  #pragma unroll
  for (int d = 0; d < 32; ++d) of[d] = 0.f;
  #pragma unroll
  for (int di = 0; di < 7; ++di) {
    #pragma unroll
    for (int dj = 0; dj < 7; ++dj) {
      const int ii = di * 7 + dj;
      const float wgt = ((pm >> ii) & 1ull) ? lg[ii] * inv : 0.f;
      const u16* vp = vt + ((rs + di) * nc + (cs + dj)) * TPAD;
      #pragma unroll
      for (int u = 0; u < 4; ++u) {
        uint4 vv = *(const uint4*)(vp + u * 8);
        axpy8(of + u * 8, wgt, vv);
      }
    }
  }
  float* op = ao + (size_t)b * (CCH * HWX) + (size_t)(h * HD) * HWX + qi * WWW + qj;
  #pragma unroll
  for (int d = 0; d < 32; ++d) op[d * HWX] = of[d];
}

// ---------------- proj GEMM: ao[b][c][hw] @ wTp -> out[b][oc][hw]
__global__ __launch_bounds__(256) void proj_kernel(
    const float* __restrict__ ao, const float* __restrict__ wTp, float* __restrict__ out) {
  __shared__ __align__(16) float xs[128 * 68];
  const int t = threadIdx.x;
  const int pg0 = blockIdx.x * 64;
  const int b = blockIdx.x >> 8;
  const int hw0 = pg0 & (HWX - 1);
  const float* xb = ao + (size_t)b * (CCH * HWX) + hw0;
  const int lp = t & 63, lc = t >> 6;
  #pragma unroll
  for (int it = 0; it < 32; ++it) {
    int c = lc + it * 4;
    xs[c * 68 + lp] = xb[(size_t)c * HWX + lp];
  }
  __syncthreads();

  const int ocg = t & 15, pixg = t >> 4;
  const int pixb = pixg * 4;
  float4 acc[8];
  #pragma unroll
  for (int o = 0; o < 8; ++o) acc[o] = make_float4(0.f, 0.f, 0.f, 0.f);

  #pragma unroll 4
  for (int c = 0; c < 128; ++c) {
    const float4 xv = *(const float4*)(xs + c * 68 + pixb);
    const float4 wA = *(const float4*)(wTp + c * 128 + ocg * 8);
    const float4 wB = *(const float4*)(wTp + c * 128 + ocg * 8 + 4);
    fma4(acc[0], wA.x, xv); fma4(acc[1], wA.y, xv);
    fma4(acc[2], wA.z, xv); fma4(acc[3], wA.w, xv);
    fma4(acc[4], wB.x, xv); fma4(acc[5], wB.y, xv);
    fma4(acc[6], wB.z, xv); fma4(acc[7], wB.w, xv);
  }
  float* ob = out + (size_t)b * (CCH * HWX) + hw0 + pixb;
  #pragma unroll
  for (int o = 0; o < 8; ++o) {
    const int oc = ocg * 8 + o;
    *(float4*)(ob + (size_t)oc * HWX) = acc[o];
  }
}

extern "C" void kernel_launch(void* const* d_in, const int* in_sizes, int n_in,
                              void* d_out, int out_size, void* d_ws, size_t ws_size,
                              hipStream_t stream) {
  const float* x      = (const float*)d_in[0];
  const float* sims   = (const float*)d_in[1];
  const float* qk_w   = (const float*)d_in[2];
  const float* v_w    = (const float*)d_in[3];
  const float* proj_w = (const float*)d_in[4];
  float* out = (float*)d_out;

  // workspace layout (bytes): q fp32 64MiB | ao fp32 64MiB | k bf16 32MiB | v bf16 32MiB | L | wT | wTp
  float* q   = (float*)d_ws;
  float* ao  = q + 16777216;
  u16*   kb  = (u16*)(ao + 16777216);
  u16*   vb  = kb + 16777216;
  int*   L   = (int*)(vb + 16777216);
  float* wT  = (float*)(L + 131072);
  float* wTp = wT + 49152;

  wtrans_kernel<<<256, 256, 0, stream>>>(qk_w, v_w, proj_w, wT, wTp);
  argmax_kernel<<<32768, 256, 0, stream>>>(sims, L);
  qkv_kernel<<<2048, 256, 0, stream>>>(x, wT, q, kb, vb);
  attn_kernel<<<2048, 256, 0, stream>>>(q, kb, vb, L, ao);
  proj_kernel<<<2048, 256, 0, stream>>>(ao, wTp, out);
}